// Round 3
// baseline (1274.905 us; speedup 1.0000x reference)
//
#include <hip/hip_runtime.h>

#define N_NODES  100000
#define N_EDGES  6400000
#define N_GRAPHS 64
#define NXCD     8

// Physical XCD id of this wave (0..7 on MI355X). Wave-uniform; a wave never
// migrates, so it safely selects an XCD-private accumulator copy.
__device__ __forceinline__ unsigned xcc_id() {
    unsigned x;
    asm("s_getreg_b32 %0, hwreg(HW_REG_XCC_ID)" : "=s"(x));
    return x & 7u;
}

// Workgroup-scope relaxed fadd: no sc1 -> executes in the XCD-local L2.
// Correct here because all updates to a given copy come from one XCD.
__device__ __forceinline__ void l2_add(float* p, float v) {
    (void)__hip_atomic_fetch_add(p, v, __ATOMIC_RELAXED, __HIP_MEMORY_SCOPE_WORKGROUP);
}

__global__ void detect_kernel(const int* ei, int* flag) {
    if (blockIdx.x == 0 && threadIdx.x == 0) {
        int allzero = 1;                       // int64 indices => hi words all 0
        for (int k = 0; k < 16; ++k)
            if (ei[2 * k + 1] != 0) allzero = 0;
        *flag = allzero ? 2 : 1;
    }
}

__global__ void zero_kernel(float* p, int n) {
    int tid = blockIdx.x * blockDim.x + threadIdx.x;
    int nth = gridDim.x * blockDim.x;
    for (int i = tid; i < n; i += nth) p[i] = 0.0f;
}

// ---- stage 1: degree ----------------------------------------------------
__global__ void deg_phase(const int* ei, const int* flag, int lo, int hi,
                          float* copies, int R) {
    const int stride = *flag;
    const int* dstp = ei + (size_t)N_EDGES * stride;
    float* my = copies + (size_t)xcc_id() * R;
    int tid = blockIdx.x * blockDim.x + threadIdx.x;
    int nth = gridDim.x * blockDim.x;
    for (int e = tid; e < N_EDGES; e += nth) {
        int d = dstp[(size_t)e * stride];
        if (d >= lo && d < hi) l2_add(&my[d - lo], 1.0f);
    }
}

__global__ void deg_reduce(const float* copies, int R, int lo, int n, float* dinv) {
    int i = blockIdx.x * blockDim.x + threadIdx.x;
    if (i >= n) return;
    float d = 1.0f;                            // self-loop
    for (int c = 0; c < NXCD; ++c) d += copies[(size_t)c * R + i];
    dinv[lo + i] = rsqrtf(d);
}

// ---- stage 2: first hop (acc1 = sum dinv[s]*x[s], accz = sum dinv[s]) ---
__global__ void edge1_phase(const int* ei, const int* flag, const float* x,
                            const float* dinv, int lo, int hi, float* copies, int R) {
    const int stride = *flag;
    const int* srcp = ei;
    const int* dstp = ei + (size_t)N_EDGES * stride;
    float* my = copies + (size_t)xcc_id() * (2 * (size_t)R);
    int tid = blockIdx.x * blockDim.x + threadIdx.x;
    int nth = gridDim.x * blockDim.x;
    for (int e = tid; e < N_EDGES; e += nth) {
        int d = dstp[(size_t)e * stride];
        if (d >= lo && d < hi) {
            int s = srcp[(size_t)e * stride];
            float v = dinv[s];
            l2_add(&my[d - lo], v * x[s]);
            l2_add(&my[R + (d - lo)], v);
        }
    }
}

// node finish for range [lo,hi): y1, z; pool z & count into gacc[64..192)
__global__ void node1_reduce(const float* x, const float* dinv, const float* copies,
                             int R, int lo, int n, const int* batch, const int* flag,
                             float* y1, float* z, float* gacc) {
    __shared__ float s[2 * N_GRAPHS];
    int t = threadIdx.x;
    for (int k = t; k < 2 * N_GRAPHS; k += blockDim.x) s[k] = 0.0f;
    __syncthreads();
    int i = blockIdx.x * blockDim.x + t;
    const int stride = *flag;
    if (i < n) {
        float a1 = 0.0f, az = 0.0f;
        for (int c = 0; c < NXCD; ++c) {
            const float* cp = copies + (size_t)c * (2 * (size_t)R);
            a1 += cp[i];
            az += cp[R + i];
        }
        int gi = lo + i;
        float di = dinv[gi];
        float yv = di * (a1 + di * x[gi]);     // (A_hat x)_i
        float zv = di * (az + di);             // (A_hat 1)_i
        y1[gi] = yv;
        z[gi]  = zv;
        int g = batch[(size_t)gi * stride];
        atomicAdd(&s[g], zv);
        atomicAdd(&s[N_GRAPHS + g], 1.0f);
    }
    __syncthreads();
    for (int k = t; k < 2 * N_GRAPHS; k += blockDim.x)
        if (s[k] != 0.0f) atomicAdd(&gacc[N_GRAPHS + k], s[k]);  // sz then cnt
}

// ---- stage 3: second hop (acc2 = sum dinv[s]*y1[s]) ---------------------
__global__ void edge2_phase(const int* ei, const int* flag, const float* dinv,
                            const float* y1, int lo, int hi, float* copies, int R) {
    const int stride = *flag;
    const int* srcp = ei;
    const int* dstp = ei + (size_t)N_EDGES * stride;
    float* my = copies + (size_t)xcc_id() * R;
    int tid = blockIdx.x * blockDim.x + threadIdx.x;
    int nth = gridDim.x * blockDim.x;
    for (int e = tid; e < N_EDGES; e += nth) {
        int d = dstp[(size_t)e * stride];
        if (d >= lo && d < hi) {
            int s = srcp[(size_t)e * stride];
            l2_add(&my[d - lo], dinv[s] * y1[s]);
        }
    }
}

// finish y2 for range and pool into gacc[0..64)
__global__ void pool2_reduce(const float* dinv, const float* y1, const float* copies,
                             int R, int lo, int n, const int* batch, const int* flag,
                             float* gacc) {
    __shared__ float s[N_GRAPHS];
    int t = threadIdx.x;
    for (int k = t; k < N_GRAPHS; k += blockDim.x) s[k] = 0.0f;
    __syncthreads();
    int i = blockIdx.x * blockDim.x + t;
    const int stride = *flag;
    if (i < n) {
        float a2 = 0.0f;
        for (int c = 0; c < NXCD; ++c) a2 += copies[(size_t)c * R + i];
        int gi = lo + i;
        float di = dinv[gi];
        float yv = di * (a2 + di * y1[gi]);    // (A_hat^2 x)_i
        atomicAdd(&s[batch[(size_t)gi * stride]], yv);
    }
    __syncthreads();
    for (int k = t; k < N_GRAPHS; k += blockDim.x)
        if (s[k] != 0.0f) atomicAdd(&gacc[k], s[k]);
}

__global__ void final_kernel(const float* W1, const float* b1, const float* W2,
                             const float* b2, const float* gacc, float* out) {
    int g = threadIdx.x;
    if (g >= N_GRAPHS) return;
    float w0 = 0.f, w1 = 0.f, c0 = 0.f, c1 = 0.f;
    for (int j = 0; j < 16; ++j) {
        float a = W2[2 * j], b = W2[2 * j + 1];
        w0 += W1[j] * a;  w1 += W1[j] * b;
        c0 += b1[j] * a;  c1 += b1[j] * b;
    }
    float sy  = gacc[g];
    float sz  = gacc[N_GRAPHS + g];
    float cnt = gacc[2 * N_GRAPHS + g];
    float inv = 1.0f / fmaxf(cnt, 1.0f);
    out[2 * g + 0] = (sy * w0 + sz * c0 + cnt * b2[0]) * inv;
    out[2 * g + 1] = (sy * w1 + sz * c1 + cnt * b2[1]) * inv;
}

extern "C" void kernel_launch(void* const* d_in, const int* in_sizes, int n_in,
                              void* d_out, int out_size, void* d_ws, size_t ws_size,
                              hipStream_t stream) {
    const float* x     = (const float*)d_in[0];
    const int*   ei    = (const int*)d_in[1];
    const int*   batch = (const int*)d_in[2];
    const float* W1    = (const float*)d_in[3];
    const float* b1    = (const float*)d_in[4];
    const float* W2    = (const float*)d_in[5];
    const float* b2    = (const float*)d_in[6];
    float* out = (float*)d_out;

    // Fixed arrays at the END of the workspace; variable copy region at start.
    const size_t N = N_NODES;
    size_t totalF = ws_size / 4;
    size_t fixedF = 3 * N + 3 * N_GRAPHS + 16;
    float* f    = (float*)d_ws;
    float* dinv = f + (totalF - fixedF);
    float* y1   = dinv + N;
    float* z    = y1 + N;
    float* gacc = z + N;
    int*   flag = (int*)(gacc + 3 * N_GRAPHS);
    long V = (long)(totalF - fixedF);          // floats available for copies
    if (V < 8 * 1024) V = 8 * 1024;            // (ws_size >= r1's 2.8MB, so V >= ~390K)

    // Phase counts: deg/edge2 need 8*R floats, edge1 needs 16*R floats.
    auto phases = [&](long per) {
        long Rmax = V / per;
        int P = (int)((N + Rmax - 1) / Rmax);
        return P < 1 ? 1 : P;
    };
    int Pd = phases(NXCD), P1 = phases(2 * NXCD), P2 = phases(NXCD);
    int Rd = (int)((N + Pd - 1) / Pd), R1 = (int)((N + P1 - 1) / P1),
        R2 = (int)((N + P2 - 1) / P2);

    const int BS = 256;
    const int edgeGrid = 2048;

    detect_kernel<<<1, 64, 0, stream>>>(ei, flag);
    zero_kernel<<<1, BS, 0, stream>>>(gacc, 3 * N_GRAPHS);

    for (int p = 0; p < Pd; ++p) {
        int lo = p * Rd, hi = lo + Rd > (int)N ? (int)N : lo + Rd, n = hi - lo;
        zero_kernel<<<512, BS, 0, stream>>>(f, NXCD * Rd);
        deg_phase<<<edgeGrid, BS, 0, stream>>>(ei, flag, lo, hi, f, Rd);
        deg_reduce<<<(n + BS - 1) / BS, BS, 0, stream>>>(f, Rd, lo, n, dinv);
    }
    for (int p = 0; p < P1; ++p) {
        int lo = p * R1, hi = lo + R1 > (int)N ? (int)N : lo + R1, n = hi - lo;
        zero_kernel<<<512, BS, 0, stream>>>(f, 2 * NXCD * R1);
        edge1_phase<<<edgeGrid, BS, 0, stream>>>(ei, flag, x, dinv, lo, hi, f, R1);
        node1_reduce<<<(n + BS - 1) / BS, BS, 0, stream>>>(x, dinv, f, R1, lo, n,
                                                           batch, flag, y1, z, gacc);
    }
    for (int p = 0; p < P2; ++p) {
        int lo = p * R2, hi = lo + R2 > (int)N ? (int)N : lo + R2, n = hi - lo;
        zero_kernel<<<512, BS, 0, stream>>>(f, NXCD * R2);
        edge2_phase<<<edgeGrid, BS, 0, stream>>>(ei, flag, dinv, y1, lo, hi, f, R2);
        pool2_reduce<<<(n + BS - 1) / BS, BS, 0, stream>>>(dinv, y1, f, R2, lo, n,
                                                           batch, flag, gacc);
    }
    final_kernel<<<1, 64, 0, stream>>>(W1, b1, W2, b2, gacc, out);
}

// Round 4
// 645.840 us; speedup vs baseline: 1.9740x; 1.9740x over previous
//
#include <hip/hip_runtime.h>

#define N_NODES  100000
#define N_EDGES  6400000
#define N_GRAPHS 64
#define NR       25024      // nodes per phase; LDS = 97.75 KB/block
#define NPHASE   4          // 4 * 25024 >= 100000
#define SCAN_BS  1024

// ---------------- utility ------------------------------------------------
__global__ void detect_kernel(const int* ei, int* flag) {
    if (blockIdx.x == 0 && threadIdx.x == 0) {
        int allzero = 1;                    // int64 indices => hi dwords all 0
        for (int k = 0; k < 16; ++k)
            if (ei[2 * k + 1] != 0) allzero = 0;
        *flag = allzero ? 2 : 1;
    }
}

__global__ void zero_gacc(float* gacc) {
    int i = threadIdx.x;
    if (i < 3 * N_GRAPHS) gacc[i] = 0.0f;
}

// ---------------- stage 1: degree (phased LDS accumulate) ----------------
__global__ __launch_bounds__(SCAN_BS)
void deg_scan(const int* ei, const int* flag, int lo, float* copies) {
    __shared__ float lds[NR];
    for (int i = threadIdx.x; i < NR; i += SCAN_BS) lds[i] = 0.0f;
    __syncthreads();
    const int stride = *flag;
    const int tid = blockIdx.x * SCAN_BS + threadIdx.x;
    const int nth = gridDim.x * SCAN_BS;
    if (stride == 2) {                       // int64: dst col, 2 edges per int4
        const int4* dp = (const int4*)(ei + (size_t)N_EDGES * 2);
        for (int q = tid; q < N_EDGES / 2; q += nth) {
            int4 v = dp[q];
            unsigned a = (unsigned)(v.x - lo); if (a < NR) atomicAdd(&lds[a], 1.0f);
            unsigned b = (unsigned)(v.z - lo); if (b < NR) atomicAdd(&lds[b], 1.0f);
        }
    } else {                                 // int32: 4 edges per int4
        const int4* dp = (const int4*)(ei + (size_t)N_EDGES);
        for (int q = tid; q < N_EDGES / 4; q += nth) {
            int4 v = dp[q];
            unsigned a = (unsigned)(v.x - lo); if (a < NR) atomicAdd(&lds[a], 1.0f);
            unsigned b = (unsigned)(v.y - lo); if (b < NR) atomicAdd(&lds[b], 1.0f);
            unsigned c = (unsigned)(v.z - lo); if (c < NR) atomicAdd(&lds[c], 1.0f);
            unsigned d = (unsigned)(v.w - lo); if (d < NR) atomicAdd(&lds[d], 1.0f);
        }
    }
    __syncthreads();
    float* my = copies + (size_t)blockIdx.x * NR;     // bulk coalesced write-out
    for (int i = threadIdx.x; i < NR; i += SCAN_BS) my[i] = lds[i];
}

// merge C copies -> dinv; build wx = dinv*x and pbt = (dinv, batch)
__global__ void deg_merge(const float* copies, int C, int lo, const float* x,
                          const int* batch, const int* flag,
                          float* wx, float2* pbt) {
    int i = blockIdx.x * blockDim.x + threadIdx.x;
    int gi = lo + i;
    if (i >= NR || gi >= N_NODES) return;
    float dsum = 1.0f;                       // self-loop
    for (int c = 0; c < C; ++c) dsum += copies[(size_t)c * NR + i];
    float di = rsqrtf(dsum);
    wx[gi] = di * x[gi];
    const int stride = *flag;
    pbt[gi] = make_float2(di, (float)batch[(size_t)gi * stride]);
}

// ---------------- stage 2: acc1 = sum_{e->i} dinv_s * x_s ----------------
__global__ __launch_bounds__(SCAN_BS)
void acc1_scan(const int* ei, const int* flag, const float* wx, int lo,
               float* copies) {
    __shared__ float lds[NR];
    for (int i = threadIdx.x; i < NR; i += SCAN_BS) lds[i] = 0.0f;
    __syncthreads();
    const int stride = *flag;
    const int tid = blockIdx.x * SCAN_BS + threadIdx.x;
    const int nth = gridDim.x * SCAN_BS;
    if (stride == 2) {
        const int* srcp = ei;
        const int4* dp = (const int4*)(ei + (size_t)N_EDGES * 2);
        for (int q = tid; q < N_EDGES / 2; q += nth) {
            int4 v = dp[q];
            unsigned a = (unsigned)(v.x - lo);
            if (a < NR) atomicAdd(&lds[a], wx[srcp[(size_t)(2 * q) * 2]]);
            unsigned b = (unsigned)(v.z - lo);
            if (b < NR) atomicAdd(&lds[b], wx[srcp[(size_t)(2 * q + 1) * 2]]);
        }
    } else {
        const int* srcp = ei;
        const int4* dp = (const int4*)(ei + (size_t)N_EDGES);
        for (int q = tid; q < N_EDGES / 4; q += nth) {
            int4 v = dp[q];
            unsigned a = (unsigned)(v.x - lo);
            if (a < NR) atomicAdd(&lds[a], wx[srcp[4 * q + 0]]);
            unsigned b = (unsigned)(v.y - lo);
            if (b < NR) atomicAdd(&lds[b], wx[srcp[4 * q + 1]]);
            unsigned c = (unsigned)(v.z - lo);
            if (c < NR) atomicAdd(&lds[c], wx[srcp[4 * q + 2]]);
            unsigned d = (unsigned)(v.w - lo);
            if (d < NR) atomicAdd(&lds[d], wx[srcp[4 * q + 3]]);
        }
    }
    __syncthreads();
    float* my = copies + (size_t)blockIdx.x * NR;
    for (int i = threadIdx.x; i < NR; i += SCAN_BS) my[i] = lds[i];
}

// merge acc1 copies -> y1; py = (dinv, y1); pool self-loop terms into gacc
__global__ void acc1_merge(const float* copies, int C, int lo, const float* wx,
                           const float2* pbt, float2* py, float* gacc) {
    __shared__ float bins[3 * N_GRAPHS];
    int t = threadIdx.x;
    for (int k = t; k < 3 * N_GRAPHS; k += blockDim.x) bins[k] = 0.0f;
    __syncthreads();
    int i = blockIdx.x * blockDim.x + t;
    int gi = lo + i;
    if (i < NR && gi < N_NODES) {
        float a1 = 0.0f;
        for (int c = 0; c < C; ++c) a1 += copies[(size_t)c * NR + i];
        float2 pb = pbt[gi];
        float di = pb.x;
        float y1 = di * (a1 + wx[gi]);       // dinv*(acc1 + dinv*x)
        py[gi] = make_float2(di, y1);
        int g = (int)pb.y;
        float di2 = di * di;
        atomicAdd(&bins[g], di2 * y1);                 // Sy self-loop term
        atomicAdd(&bins[N_GRAPHS + g], di2);           // Sz self-loop term
        atomicAdd(&bins[2 * N_GRAPHS + g], 1.0f);      // count
    }
    __syncthreads();
    for (int k = t; k < 3 * N_GRAPHS; k += blockDim.x)
        if (bins[k] != 0.0f) atomicAdd(&gacc[k], bins[k]);
}

// ---------------- stage 3: edge pool into 64 graph bins ------------------
__global__ __launch_bounds__(SCAN_BS)
void pool_scan(const int* ei, const int* flag, const float2* py,
               const float2* pbt, float* gacc) {
    __shared__ float bins[2 * N_GRAPHS];
    int t = threadIdx.x;
    for (int k = t; k < 2 * N_GRAPHS; k += SCAN_BS) bins[k] = 0.0f;
    __syncthreads();
    const int stride = *flag;
    const int tid = blockIdx.x * SCAN_BS + t;
    const int nth = gridDim.x * SCAN_BS;
    if (stride == 2) {
        const int4* sp = (const int4*)ei;
        const int4* dp = (const int4*)(ei + (size_t)N_EDGES * 2);
        for (int q = tid; q < N_EDGES / 2; q += nth) {
            int4 sv = sp[q], dv = dp[q];
            {   float2 ps = py[sv.x]; float2 pd = pbt[dv.x];
                float w = pd.x * ps.x; int g = (int)pd.y;
                atomicAdd(&bins[g], w * ps.y); atomicAdd(&bins[N_GRAPHS + g], w); }
            {   float2 ps = py[sv.z]; float2 pd = pbt[dv.z];
                float w = pd.x * ps.x; int g = (int)pd.y;
                atomicAdd(&bins[g], w * ps.y); atomicAdd(&bins[N_GRAPHS + g], w); }
        }
    } else {
        const int4* sp = (const int4*)ei;
        const int4* dp = (const int4*)(ei + (size_t)N_EDGES);
        for (int q = tid; q < N_EDGES / 4; q += nth) {
            int4 sv = sp[q], dv = dp[q];
            int ss[4] = {sv.x, sv.y, sv.z, sv.w};
            int dd[4] = {dv.x, dv.y, dv.z, dv.w};
            #pragma unroll
            for (int k = 0; k < 4; ++k) {
                float2 ps = py[ss[k]]; float2 pd = pbt[dd[k]];
                float w = pd.x * ps.x; int g = (int)pd.y;
                atomicAdd(&bins[g], w * ps.y); atomicAdd(&bins[N_GRAPHS + g], w);
            }
        }
    }
    __syncthreads();
    for (int k = t; k < 2 * N_GRAPHS; k += SCAN_BS)
        if (bins[k] != 0.0f) atomicAdd(&gacc[k], bins[k]);
}

// ---------------- final --------------------------------------------------
__global__ void final_kernel(const float* W1, const float* b1, const float* W2,
                             const float* b2, const float* gacc, float* out) {
    int g = threadIdx.x;
    if (g >= N_GRAPHS) return;
    float w0 = 0.f, w1 = 0.f, c0 = 0.f, c1 = 0.f;
    for (int j = 0; j < 16; ++j) {
        float a = W2[2 * j], b = W2[2 * j + 1];
        w0 += W1[j] * a;  w1 += W1[j] * b;
        c0 += b1[j] * a;  c1 += b1[j] * b;
    }
    float sy  = gacc[g];
    float sz  = gacc[N_GRAPHS + g];
    float cnt = gacc[2 * N_GRAPHS + g];
    float inv = 1.0f / fmaxf(cnt, 1.0f);
    out[2 * g + 0] = (sy * w0 + sz * c0 + cnt * b2[0]) * inv;
    out[2 * g + 1] = (sy * w1 + sz * c1 + cnt * b2[1]) * inv;
}

extern "C" void kernel_launch(void* const* d_in, const int* in_sizes, int n_in,
                              void* d_out, int out_size, void* d_ws, size_t ws_size,
                              hipStream_t stream) {
    const float* x     = (const float*)d_in[0];
    const int*   ei    = (const int*)d_in[1];
    const int*   batch = (const int*)d_in[2];
    const float* W1    = (const float*)d_in[3];
    const float* b1    = (const float*)d_in[4];
    const float* W2    = (const float*)d_in[5];
    const float* b2    = (const float*)d_in[6];
    float* out = (float*)d_out;

    // Workspace layout: wx[N] | py[N]f2 | pbt[N]f2 | gacc[192] | flag | copies...
    float*  f    = (float*)d_ws;
    float*  wx   = f;
    float2* py   = (float2*)(wx + N_NODES);
    float2* pbt  = py + N_NODES;
    float*  gacc = (float*)(pbt + N_NODES);
    int*    flag = (int*)(gacc + 3 * N_GRAPHS);
    float*  copies = (float*)(flag + 16);

    const size_t fixedF = 5 * (size_t)N_NODES + 3 * N_GRAPHS + 16;
    long availF = (long)(ws_size / 4) - (long)fixedF;
    int C = (int)(availF / NR);              // private copies == scan blocks
    if (C > 192) C = 192;
    if (C < 8)   C = 8;                      // (ws >= 7.6MB proven -> C >= 55)

    const int mergeBS = 256;
    const int mergeGrid = (NR + mergeBS - 1) / mergeBS;

    detect_kernel<<<1, 64, 0, stream>>>(ei, flag);
    zero_gacc<<<1, 3 * N_GRAPHS, 0, stream>>>(gacc);

    for (int p = 0; p < NPHASE; ++p) {
        int lo = p * NR;
        deg_scan<<<C, SCAN_BS, 0, stream>>>(ei, flag, lo, copies);
        deg_merge<<<mergeGrid, mergeBS, 0, stream>>>(copies, C, lo, x, batch,
                                                     flag, wx, pbt);
    }
    for (int p = 0; p < NPHASE; ++p) {
        int lo = p * NR;
        acc1_scan<<<C, SCAN_BS, 0, stream>>>(ei, flag, wx, lo, copies);
        acc1_merge<<<mergeGrid, mergeBS, 0, stream>>>(copies, C, lo, wx, pbt,
                                                      py, gacc);
    }
    pool_scan<<<256, SCAN_BS, 0, stream>>>(ei, flag, py, pbt, gacc);
    final_kernel<<<1, 64, 0, stream>>>(W1, b1, W2, b2, gacc, out);
}

// Round 5
// 330.989 us; speedup vs baseline: 3.8518x; 1.9512x over previous
//
#include <hip/hip_runtime.h>

#define N_NODES  100000
#define N_EDGES  6400000
#define N_GRAPHS 64
#define SCAN_BS  1024

// ---------------- utility ------------------------------------------------
__global__ void detect_kernel(const int* ei, int* flag) {
    if (blockIdx.x == 0 && threadIdx.x == 0) {
        int allzero = 1;                    // int64 indices => hi dwords all 0
        for (int k = 0; k < 16; ++k)
            if (ei[2 * k + 1] != 0) allzero = 0;
        *flag = allzero ? 2 : 1;
    }
}

__global__ void zero_gacc(float* gacc) {
    int i = threadIdx.x;
    if (i < 3 * N_GRAPHS) gacc[i] = 0.0f;
}

// ---------------- stage 1: degree, u16-packed LDS bins -------------------
template <int NR>
__global__ __launch_bounds__(SCAN_BS)
void deg_scan(const int* ei, const int* flag, int lo, unsigned* copies) {
    constexpr int W = NR / 2;
    __shared__ unsigned bins[W];
    for (int i = threadIdx.x; i < W; i += SCAN_BS) bins[i] = 0u;
    __syncthreads();
    const int stride = *flag;
    const int tid = blockIdx.x * SCAN_BS + threadIdx.x;
    const int nth = gridDim.x * SCAN_BS;
    if (stride == 2) {                      // int64 dst col: 2 edges / int4
        const int4* dp = (const int4*)(ei + (size_t)N_EDGES * 2);
        int q = tid;
        for (; q + nth < N_EDGES / 2; q += 2 * nth) {
            int4 v0 = dp[q], v1 = dp[q + nth];
            unsigned a0 = (unsigned)(v0.x - lo), b0 = (unsigned)(v0.z - lo);
            unsigned a1 = (unsigned)(v1.x - lo), b1 = (unsigned)(v1.z - lo);
            if (a0 < NR) atomicAdd(&bins[a0 >> 1], 1u << (16 * (a0 & 1)));
            if (b0 < NR) atomicAdd(&bins[b0 >> 1], 1u << (16 * (b0 & 1)));
            if (a1 < NR) atomicAdd(&bins[a1 >> 1], 1u << (16 * (a1 & 1)));
            if (b1 < NR) atomicAdd(&bins[b1 >> 1], 1u << (16 * (b1 & 1)));
        }
        for (; q < N_EDGES / 2; q += nth) {
            int4 v = dp[q];
            unsigned a = (unsigned)(v.x - lo), b = (unsigned)(v.z - lo);
            if (a < NR) atomicAdd(&bins[a >> 1], 1u << (16 * (a & 1)));
            if (b < NR) atomicAdd(&bins[b >> 1], 1u << (16 * (b & 1)));
        }
    } else {                                // int32 dst col: 4 edges / int4
        const int4* dp = (const int4*)(ei + (size_t)N_EDGES);
        for (int q = tid; q < N_EDGES / 4; q += nth) {
            int4 v = dp[q];
            unsigned a = (unsigned)(v.x - lo), b = (unsigned)(v.y - lo);
            unsigned c = (unsigned)(v.z - lo), d = (unsigned)(v.w - lo);
            if (a < NR) atomicAdd(&bins[a >> 1], 1u << (16 * (a & 1)));
            if (b < NR) atomicAdd(&bins[b >> 1], 1u << (16 * (b & 1)));
            if (c < NR) atomicAdd(&bins[c >> 1], 1u << (16 * (c & 1)));
            if (d < NR) atomicAdd(&bins[d >> 1], 1u << (16 * (d & 1)));
        }
    }
    __syncthreads();
    unsigned* my = copies + (size_t)blockIdx.x * W;
    for (int i = threadIdx.x; i < W; i += SCAN_BS) my[i] = bins[i];
}

// merge C u16-packed copies -> dinv; build wx = dinv*x, pbt = (dinv, batch)
// grid: ceil(range/64), block 256 (64 nodes x 4 C-chunks)
__global__ void deg_merge(const unsigned* copies, int W, int C, int lo,
                          const float* x, const int* batch, const int* flag,
                          float* wx, float2* pbt) {
    __shared__ float red[256];
    int il = threadIdx.x & 63, cs = threadIdx.x >> 6;
    int i = blockIdx.x * 64 + il;
    int gi = lo + i;
    bool ok = (i < 2 * W) && (gi < N_NODES);
    float partial = 0.0f;
    if (ok) {
        int sh = 16 * (i & 1), w = i >> 1;
        for (int c = cs; c < C; c += 4)
            partial += (float)((copies[(size_t)c * W + w] >> sh) & 0xFFFFu);
    }
    red[threadIdx.x] = partial;
    __syncthreads();
    if (cs == 0 && ok) {
        float d = 1.0f + red[il] + red[64 + il] + red[128 + il] + red[192 + il];
        float di = rsqrtf(d);
        wx[gi] = di * x[gi];
        const int stride = *flag;
        pbt[gi] = make_float2(di, (float)batch[(size_t)gi * stride]);
    }
}

// ---------------- stage 2: acc1 = sum_{e->i} dinv_s * x_s ----------------
template <int NR>
__global__ __launch_bounds__(SCAN_BS)
void acc1_scan(const int* ei, const int* flag, const float* wx, int lo,
               float* copies) {
    __shared__ float bins[NR];
    for (int i = threadIdx.x; i < NR; i += SCAN_BS) bins[i] = 0.0f;
    __syncthreads();
    const int stride = *flag;
    const int tid = blockIdx.x * SCAN_BS + threadIdx.x;
    const int nth = gridDim.x * SCAN_BS;
    if (stride == 2) {
        const int* srcp = ei;
        const int4* dp = (const int4*)(ei + (size_t)N_EDGES * 2);
        int q = tid;
        for (; q + nth < N_EDGES / 2; q += 2 * nth) {
            int4 v0 = dp[q], v1 = dp[q + nth];
            unsigned a0 = (unsigned)(v0.x - lo), b0 = (unsigned)(v0.z - lo);
            unsigned a1 = (unsigned)(v1.x - lo), b1 = (unsigned)(v1.z - lo);
            if (a0 < NR) atomicAdd(&bins[a0], wx[srcp[(size_t)4 * q]]);
            if (b0 < NR) atomicAdd(&bins[b0], wx[srcp[(size_t)4 * q + 2]]);
            if (a1 < NR) atomicAdd(&bins[a1], wx[srcp[(size_t)4 * (q + nth)]]);
            if (b1 < NR) atomicAdd(&bins[b1], wx[srcp[(size_t)4 * (q + nth) + 2]]);
        }
        for (; q < N_EDGES / 2; q += nth) {
            int4 v = dp[q];
            unsigned a = (unsigned)(v.x - lo), b = (unsigned)(v.z - lo);
            if (a < NR) atomicAdd(&bins[a], wx[srcp[(size_t)4 * q]]);
            if (b < NR) atomicAdd(&bins[b], wx[srcp[(size_t)4 * q + 2]]);
        }
    } else {
        const int* srcp = ei;
        const int4* dp = (const int4*)(ei + (size_t)N_EDGES);
        for (int q = tid; q < N_EDGES / 4; q += nth) {
            int4 v = dp[q];
            unsigned a = (unsigned)(v.x - lo), b = (unsigned)(v.y - lo);
            unsigned c = (unsigned)(v.z - lo), d = (unsigned)(v.w - lo);
            if (a < NR) atomicAdd(&bins[a], wx[srcp[4 * q + 0]]);
            if (b < NR) atomicAdd(&bins[b], wx[srcp[4 * q + 1]]);
            if (c < NR) atomicAdd(&bins[c], wx[srcp[4 * q + 2]]);
            if (d < NR) atomicAdd(&bins[d], wx[srcp[4 * q + 3]]);
        }
    }
    __syncthreads();
    float* my = copies + (size_t)blockIdx.x * NR;
    for (int i = threadIdx.x; i < NR; i += SCAN_BS) my[i] = bins[i];
}

// merge acc1 copies -> py=(dinv,y1); pool self-loop terms into gacc
__global__ void acc1_merge(const float* copies, int NR, int C, int lo,
                           const float* wx, const float2* pbt,
                           float2* py, float* gacc) {
    __shared__ float red[256];
    __shared__ float bins[3 * N_GRAPHS];
    int t = threadIdx.x;
    for (int k = t; k < 3 * N_GRAPHS; k += 256) bins[k] = 0.0f;
    int il = t & 63, cs = t >> 6;
    int i = blockIdx.x * 64 + il;
    int gi = lo + i;
    bool ok = (i < NR) && (gi < N_NODES);
    float partial = 0.0f;
    if (ok)
        for (int c = cs; c < C; c += 4) partial += copies[(size_t)c * NR + i];
    red[t] = partial;
    __syncthreads();
    if (cs == 0 && ok) {
        float a1 = red[il] + red[64 + il] + red[128 + il] + red[192 + il];
        float2 pb = pbt[gi];
        float di = pb.x;
        float y1 = di * (a1 + wx[gi]);       // dinv*(acc1 + dinv*x)
        py[gi] = make_float2(di, y1);
        int g = (int)pb.y;
        float di2 = di * di;
        atomicAdd(&bins[g], di2 * y1);                 // Sy self-loop
        atomicAdd(&bins[N_GRAPHS + g], di2);           // Sz self-loop
        atomicAdd(&bins[2 * N_GRAPHS + g], 1.0f);      // count
    }
    __syncthreads();
    for (int k = t; k < 3 * N_GRAPHS; k += 256)
        if (bins[k] != 0.0f) atomicAdd(&gacc[k], bins[k]);
}

// ---------------- stage 3: edge pool, per-warp bins ----------------------
#define PW 16
__global__ __launch_bounds__(SCAN_BS)
void pool_scan(const int* ei, const int* flag, const float2* py,
               const float2* pbt, float* gacc) {
    __shared__ float wb[PW][2 * N_GRAPHS];
    int t = threadIdx.x;
    for (int k = t; k < PW * 2 * N_GRAPHS; k += SCAN_BS) ((float*)wb)[k] = 0.0f;
    __syncthreads();
    float* mb = wb[t >> 6];
    const int stride = *flag;
    const int tid = blockIdx.x * SCAN_BS + t;
    const int nth = gridDim.x * SCAN_BS;
    if (stride == 2) {
        const int4* sp = (const int4*)ei;
        const int4* dp = (const int4*)(ei + (size_t)N_EDGES * 2);
        int q = tid;
        for (; q + nth < N_EDGES / 2; q += 2 * nth) {
            int4 s0 = sp[q], d0 = dp[q], s1 = sp[q + nth], d1 = dp[q + nth];
            float2 pa0 = py[s0.x], pb0 = pbt[d0.x];
            float2 pa1 = py[s0.z], pb1 = pbt[d0.z];
            float2 pa2 = py[s1.x], pb2 = pbt[d1.x];
            float2 pa3 = py[s1.z], pb3 = pbt[d1.z];
            float w0 = pb0.x * pa0.x, w1 = pb1.x * pa1.x;
            float w2 = pb2.x * pa2.x, w3 = pb3.x * pa3.x;
            int g0 = (int)pb0.y, g1 = (int)pb1.y, g2 = (int)pb2.y, g3 = (int)pb3.y;
            atomicAdd(&mb[g0], w0 * pa0.y); atomicAdd(&mb[N_GRAPHS + g0], w0);
            atomicAdd(&mb[g1], w1 * pa1.y); atomicAdd(&mb[N_GRAPHS + g1], w1);
            atomicAdd(&mb[g2], w2 * pa2.y); atomicAdd(&mb[N_GRAPHS + g2], w2);
            atomicAdd(&mb[g3], w3 * pa3.y); atomicAdd(&mb[N_GRAPHS + g3], w3);
        }
        for (; q < N_EDGES / 2; q += nth) {
            int4 sv = sp[q], dv = dp[q];
            float2 pa0 = py[sv.x], pb0 = pbt[dv.x];
            float2 pa1 = py[sv.z], pb1 = pbt[dv.z];
            float w0 = pb0.x * pa0.x, w1 = pb1.x * pa1.x;
            int g0 = (int)pb0.y, g1 = (int)pb1.y;
            atomicAdd(&mb[g0], w0 * pa0.y); atomicAdd(&mb[N_GRAPHS + g0], w0);
            atomicAdd(&mb[g1], w1 * pa1.y); atomicAdd(&mb[N_GRAPHS + g1], w1);
        }
    } else {
        const int4* sp = (const int4*)ei;
        const int4* dp = (const int4*)(ei + (size_t)N_EDGES);
        for (int q = tid; q < N_EDGES / 4; q += nth) {
            int4 sv = sp[q], dv = dp[q];
            int ss[4] = {sv.x, sv.y, sv.z, sv.w};
            int dd[4] = {dv.x, dv.y, dv.z, dv.w};
            #pragma unroll
            for (int k = 0; k < 4; ++k) {
                float2 pa = py[ss[k]]; float2 pb = pbt[dd[k]];
                float w = pb.x * pa.x; int g = (int)pb.y;
                atomicAdd(&mb[g], w * pa.y); atomicAdd(&mb[N_GRAPHS + g], w);
            }
        }
    }
    __syncthreads();
    for (int k = t; k < 2 * N_GRAPHS; k += SCAN_BS) {
        float s = 0.0f;
        for (int w = 0; w < PW; ++w) s += wb[w][k];
        if (s != 0.0f) atomicAdd(&gacc[k], s);
    }
}

// ---------------- final --------------------------------------------------
__global__ void final_kernel(const float* W1, const float* b1, const float* W2,
                             const float* b2, const float* gacc, float* out) {
    int g = threadIdx.x;
    if (g >= N_GRAPHS) return;
    float w0 = 0.f, w1 = 0.f, c0 = 0.f, c1 = 0.f;
    for (int j = 0; j < 16; ++j) {
        float a = W2[2 * j], b = W2[2 * j + 1];
        w0 += W1[j] * a;  w1 += W1[j] * b;
        c0 += b1[j] * a;  c1 += b1[j] * b;
    }
    float sy  = gacc[g];
    float sz  = gacc[N_GRAPHS + g];
    float cnt = gacc[2 * N_GRAPHS + g];
    float inv = 1.0f / fmaxf(cnt, 1.0f);
    out[2 * g + 0] = (sy * w0 + sz * c0 + cnt * b2[0]) * inv;
    out[2 * g + 1] = (sy * w1 + sz * c1 + cnt * b2[1]) * inv;
}

extern "C" void kernel_launch(void* const* d_in, const int* in_sizes, int n_in,
                              void* d_out, int out_size, void* d_ws, size_t ws_size,
                              hipStream_t stream) {
    const float* x     = (const float*)d_in[0];
    const int*   ei    = (const int*)d_in[1];
    const int*   batch = (const int*)d_in[2];
    const float* W1    = (const float*)d_in[3];
    const float* b1    = (const float*)d_in[4];
    const float* W2    = (const float*)d_in[5];
    const float* b2    = (const float*)d_in[6];
    float* out = (float*)d_out;

    // ws: wx[N] | py[N]f2 | pbt[N]f2 | gacc[192] | flag[16] | copies...
    float*  f    = (float*)d_ws;
    float*  wx   = f;
    float2* py   = (float2*)(wx + N_NODES);
    float2* pbt  = py + N_NODES;
    float*  gacc = (float*)(pbt + N_NODES);
    int*    flag = (int*)(gacc + 3 * N_GRAPHS);
    float*  copies = (float*)(flag + 16);

    const long fixedF = 5L * N_NODES + 3 * N_GRAPHS + 16;
    long availF = (long)(ws_size / 4) - fixedF;
    if (availF < 200000) availF = 200000;   // ws >= 7.6MB proven in r3

    // Pick bin sizes: smallest phase count with grid C >= 160 (cap 256).
    const int degOpts[] = {50048, 33408, 25024, 16704, 12512, 8352};
    const int accOpts[] = {25024, 16704, 12512, 8352, 6272, 4160};
    int NRD = degOpts[5], NRA = accOpts[5];
    for (int v : degOpts) if (availF / (v / 2) >= 160) { NRD = v; break; }
    for (int v : accOpts) if (availF / v >= 160)       { NRA = v; break; }
    long CD = availF / (NRD / 2); if (CD > 256) CD = 256; if (CD < 8) CD = 8;
    long CA = availF / NRA;       if (CA > 256) CA = 256; if (CA < 8) CA = 8;
    const int PD = (N_NODES + NRD - 1) / NRD;
    const int PA = (N_NODES + NRA - 1) / NRA;

    detect_kernel<<<1, 64, 0, stream>>>(ei, flag);
    zero_gacc<<<1, 3 * N_GRAPHS, 0, stream>>>(gacc);

    #define DEG_LAUNCH(NRV) deg_scan<NRV><<<(int)CD, SCAN_BS, 0, stream>>>( \
        ei, flag, lo, (unsigned*)copies)
    for (int p = 0; p < PD; ++p) {
        int lo = p * NRD;
        switch (NRD) {
            case 50048: DEG_LAUNCH(50048); break;
            case 33408: DEG_LAUNCH(33408); break;
            case 25024: DEG_LAUNCH(25024); break;
            case 16704: DEG_LAUNCH(16704); break;
            case 12512: DEG_LAUNCH(12512); break;
            default:    DEG_LAUNCH(8352);  break;
        }
        int range = (N_NODES - lo < NRD) ? (N_NODES - lo) : NRD;
        deg_merge<<<(range + 63) / 64, 256, 0, stream>>>(
            (unsigned*)copies, NRD / 2, (int)CD, lo, x, batch, flag, wx, pbt);
    }

    #define ACC_LAUNCH(NRV) acc1_scan<NRV><<<(int)CA, SCAN_BS, 0, stream>>>( \
        ei, flag, wx, lo, copies)
    for (int p = 0; p < PA; ++p) {
        int lo = p * NRA;
        switch (NRA) {
            case 25024: ACC_LAUNCH(25024); break;
            case 16704: ACC_LAUNCH(16704); break;
            case 12512: ACC_LAUNCH(12512); break;
            case 8352:  ACC_LAUNCH(8352);  break;
            case 6272:  ACC_LAUNCH(6272);  break;
            default:    ACC_LAUNCH(4160);  break;
        }
        int range = (N_NODES - lo < NRA) ? (N_NODES - lo) : NRA;
        acc1_merge<<<(range + 63) / 64, 256, 0, stream>>>(
            copies, NRA, (int)CA, lo, wx, pbt, py, gacc);
    }

    pool_scan<<<512, SCAN_BS, 0, stream>>>(ei, flag, py, pbt, gacc);
    final_kernel<<<1, 64, 0, stream>>>(W1, b1, W2, b2, gacc, out);
}